// Round 22
// baseline (230.906 us; speedup 1.0000x reference)
//
#include <hip/hip_runtime.h>
#include <hip/hip_bf16.h>

#define B_TOK 16384
#define TOPK 2
#define NEXP 64
#define HID 512
#define FFN 1024
#define NASSIGN (B_TOK * TOPK)   // 32768
#define CAP (NASSIGN / NEXP)     // 512 assignments per expert (balanced)

typedef unsigned short u16;
typedef __bf16 bf16_t;
typedef bf16_t bf16x8 __attribute__((ext_vector_type(8)));
typedef float f32x4 __attribute__((ext_vector_type(4)));

// native cvt: compiler emits v_cvt_pk_bf16_f32 (RTNE)
__device__ __forceinline__ unsigned pkbf(float a, float b) {
  union { bf16_t h[2]; unsigned u; } v;
  v.h[0] = (bf16_t)a; v.h[1] = (bf16_t)b;
  return v.u;
}
__device__ __forceinline__ u16 f2bf(float f) {
  union { bf16_t h; u16 u; } v; v.h = (bf16_t)f; return v.u;
}
__device__ __forceinline__ float bf2f(unsigned u16v) {
  union { unsigned u; float f; } v; v.u = u16v << 16; return v.f;
}

#define GLOAD_LDS16(g, l)                                                     \
  __builtin_amdgcn_global_load_lds((const __attribute__((address_space(1))) void*)(g), \
                                   (__attribute__((address_space(3))) void*)(l), 16, 0, 0)

// ---------------------------------------------------------------- routing
__global__ void k_route(const int* __restrict__ ids, int* __restrict__ cnt,
                        int* __restrict__ tok_of, int* __restrict__ slot_pos) {
  int n = blockIdx.x * blockDim.x + threadIdx.x;
  if (n >= NASSIGN) return;
  int e = ids[n];
  int r = atomicAdd(&cnt[e], 1);
  int p = e * CAP + r;
  tok_of[p] = n >> 1;       // token index for sorted slot p
  slot_pos[n] = p;          // inverse map: assignment n -> sorted slot
}

// ------------------------------------------------- gather + fp32->bf16 cast
__global__ void k_gather(const float* __restrict__ hs, const int* __restrict__ tok_of,
                         u16* __restrict__ Xg) {
  int p = blockIdx.x * 4 + (threadIdx.x >> 6);
  int lane = threadIdx.x & 63;
  const float4* src = reinterpret_cast<const float4*>(hs + (size_t)tok_of[p] * HID);
  uint2* dst = reinterpret_cast<uint2*>(Xg + (size_t)p * HID);
#pragma unroll
  for (int i = 0; i < 2; i++) {
    float4 v = src[i * 64 + lane];
    uint2 o;
    o.x = pkbf(v.x, v.y);
    o.y = pkbf(v.z, v.w);
    dst[i * 64 + lane] = o;
  }
}

// ------------------------------------------------------------ grouped GEMM
// 256x128 tile, BK=32, 8 waves (4Mx2N, per-wave 64x64 -> acc[4][4]=64 VGPR),
// LDS 48KB (A dbuf 2x16KB at 0, B dbuf 2x8KB at 32768), launch_bounds(512,4)
// -> VGPR cap 128 (feasible: ~125 est) -> 2 blocks/CU for cross-block TLP.
// R18 2-phase loop, ONE barrier per K-tile:
//   LOAD_L(t+1) [8 fp32 dwords] ; STAGE_A(t+1) -> OPPOSITE A-slot [2 DMA]
//   read a[4]+b[4] (8 ds_read_b128) ; lgkm0 ; 16 MFMA ;
//   vmcnt(4) [queue 8L+2ADMA... compiler adds reg-dep waits for L anyway] ;
//   WRITE_B(t+1) [1 uint4 swizzled] ; vmcnt(0)+lgkm0 ; s_barrier.
// LDS layout (R11-verified, measured 0 conflicts): logical (row r, 16B chunk
// c in 0..3) at byte (r>>1)*128 + ((4*(r&1)+c) ^ ((r>>1)&7))*16.
//  - A staged via global_load_lds with inverse-decoded per-lane SOURCE
//    (rule #21: linear LDS dest).
//  - B writes: thread -> col n=t&127, chunk kg=t>>7; slot=((n&1)*4+kg)^((n>>1)&7).
//  - frag reads use the same formula (chunk = lhi).
template <int K, int NN, bool SILU>
__global__ __launch_bounds__(512, 4) void k_gemm(const u16* __restrict__ A,
                                                 const float* __restrict__ Wf,
                                                 u16* __restrict__ Cout) {
  constexpr int MT = CAP / 256;        // 2
  constexpr int NT = NN / 128;         // 8 (G1) / 4 (G2)
  constexpr int NWG = NEXP * MT * NT;  // %8 == 0
  constexpr int Q = NWG / 8;
  constexpr int KT = K / 32;           // 16 / 32
  int wg = (blockIdx.x % 8) * Q + blockIdx.x / 8;  // XCD chunked swizzle
  int e = wg / (MT * NT);
  int rm = wg % (MT * NT);
  int mt = rm / NT, nt = rm % NT;

  const u16* Ab = A + ((size_t)e * CAP + (size_t)mt * 256) * K;

  // LDS: A dbuf 2x16KB at 0; B dbuf 2x8KB at 32768. 48KB.
  __shared__ __align__(16) char smc[49152];

  int t_ = threadIdx.x;
  int lane = t_ & 63, wv = t_ >> 6;
  int wm = wv >> 1, wn = wv & 1;        // 4x2 wave grid; wave out = 64x64
  int l15 = lane & 15, lhi = lane >> 4;

  // ---- A staging: DMA call j covers rows j*128..+127 (8KB); thread t_ ->
  // phys chunk t_ (byte t_*16).  Decode phys m -> logical (r,c):
  // pair=m>>3, x=(m&7)^(pair&7), r=2*pair+(x>>2), c=x&3.
  int pr0 = t_ >> 3, x0 = (t_ & 7) ^ (pr0 & 7);
  const u16* gA0 = Ab + (size_t)(2 * pr0 + (x0 >> 2)) * K + (x0 & 3) * 8;
  const u16* gA1 = gA0 + (size_t)128 * K;   // rows +128, same swizzle bits
#define STAGE_A(tn)                                                          \
  do {                                                                       \
    char* d_ = smc + ((tn) & 1) * 16384 + wv * 1024;                         \
    GLOAD_LDS16(gA0 + (size_t)(tn) * 32, d_);                                \
    GLOAD_LDS16(gA1 + (size_t)(tn) * 32, d_ + 8192);                         \
  } while (0)

  // ---- B staging: thread -> col ncol = t_&127, k-oct kg = t_>>7 (0..3);
  // wave = 64 consecutive cols, same kg -> coalesced dword loads.
  int ncol = t_ & 127, kg = t_ >> 7;
  const float* gWb = Wf + (size_t)e * K * NN + (size_t)(kg * 8) * NN +
                     (size_t)nt * 128 + ncol;
  int wbo = (ncol >> 1) * 128 + ((((ncol & 1) * 4 + kg) ^ ((ncol >> 1) & 7)) << 4);
  float L[8];
#define LOAD_L(tn)                                                           \
  do {                                                                       \
    const float* g_ = gWb + (size_t)(tn) * 32 * NN;                          \
    _Pragma("unroll") for (int j = 0; j < 8; j++) L[j] = g_[(size_t)j * NN]; \
  } while (0)
#define WRITE_B(tn)                                                          \
  do {                                                                       \
    char* w_ = smc + 32768 + ((tn) & 1) * 8192;                              \
    uint4 v;                                                                 \
    v.x = pkbf(L[0], L[1]); v.y = pkbf(L[2], L[3]);                          \
    v.z = pkbf(L[4], L[5]); v.w = pkbf(L[6], L[7]);                          \
    *reinterpret_cast<uint4*>(w_ + wbo) = v;                                 \
  } while (0)

  f32x4 acc[4][4];
#pragma unroll
  for (int i = 0; i < 4; i++)
#pragma unroll
    for (int j = 0; j < 4; j++) {
      f32x4 z = {0.f, 0.f, 0.f, 0.f};
      acc[i][j] = z;
    }
  bf16x8 a[4], b[4];

  // ---- fragment read offsets (swizzled layout; chunk = lhi)
  int aof[4], bof[4];
#pragma unroll
  for (int f = 0; f < 4; f++) {
    int ar = wm * 64 + f * 16 + l15;
    aof[f] = (ar >> 1) * 128 + ((((ar & 1) * 4 + lhi) ^ ((ar >> 1) & 7)) << 4);
    int br = wn * 64 + f * 16 + l15;
    bof[f] = (br >> 1) * 128 + ((((br & 1) * 4 + lhi) ^ ((br >> 1) & 7)) << 4);
  }

#define LGKM0()                                                              \
  do {                                                                       \
    asm volatile("s_waitcnt lgkmcnt(0)" ::: "memory");                       \
    __builtin_amdgcn_sched_barrier(0);                                       \
  } while (0)

  // ---- prologue: A(0) DMA; L(0) -> B slot 0
  STAGE_A(0);
  LOAD_L(0);
  asm volatile("s_waitcnt vmcnt(0)" ::: "memory");  // L(0) regs + A(0) resident
  __builtin_amdgcn_sched_barrier(0);
  WRITE_B(0);
  LGKM0();
  __builtin_amdgcn_s_barrier();

  for (int t = 0; t < KT; t++) {
    const char* pA = smc + (t & 1) * 16384;
    const char* pB = smc + 32768 + (t & 1) * 8192;

    // issue next-tile loads first: 8 L (oldest), then 2 A-DMA
    if (t + 1 < KT) {
      LOAD_L(t + 1);
      STAGE_A(t + 1);
    }

    // ---- frags + 16 MFMA
#pragma unroll
    for (int f = 0; f < 4; f++) {
      a[f] = *reinterpret_cast<const bf16x8*>(pA + aof[f]);
      b[f] = *reinterpret_cast<const bf16x8*>(pB + bof[f]);
    }
    LGKM0();
#pragma unroll
    for (int mf = 0; mf < 4; mf++)
#pragma unroll
      for (int nf = 0; nf < 4; nf++)
        acc[mf][nf] = __builtin_amdgcn_mfma_f32_16x16x32_bf16(a[mf], b[nf], acc[mf][nf], 0, 0, 0);

    // ---- stage B(t+1) from L regs; single barrier
    if (t + 1 < KT) {
      asm volatile("s_waitcnt vmcnt(4)" ::: "memory");  // L retired (compiler adds reg-dep waits too)
      __builtin_amdgcn_sched_barrier(0);
      WRITE_B(t + 1);
      asm volatile("s_waitcnt vmcnt(0) lgkmcnt(0)" ::: "memory");  // ADMA + B-writes drained
      __builtin_amdgcn_sched_barrier(0);
      __builtin_amdgcn_s_barrier();
    }
  }
#undef STAGE_A
#undef LOAD_L
#undef WRITE_B
#undef LGKM0

  // epilogue: D row = lhi*4+reg, col = l15 (verified C/D layout); bf16 out
#pragma unroll
  for (int mf = 0; mf < 4; mf++) {
#pragma unroll
    for (int nf = 0; nf < 4; nf++) {
#pragma unroll
      for (int rg = 0; rg < 4; rg++) {
        float v = acc[mf][nf][rg];
        int grow = mt * 256 + wm * 64 + mf * 16 + lhi * 4 + rg;
        int gcol = nt * 128 + wn * 64 + nf * 16 + l15;
        size_t off = ((size_t)e * CAP + grow) * NN + gcol;
        if constexpr (SILU) v = v / (1.0f + __expf(-v));  // silu
        Cout[off] = f2bf(v);
      }
    }
  }
}

// ------------------------------------------- weighted combine (no atomics)
// wave per token: lane reads uint4 (8 bf16) per slot row, writes 2 float4.
__global__ void k_combine(const u16* __restrict__ yws, const int* __restrict__ slot_pos,
                          const float* __restrict__ w, float* __restrict__ out) {
  int tk = blockIdx.x * 4 + (threadIdx.x >> 6);
  int lane = threadIdx.x & 63;
  int p0 = slot_pos[2 * tk], p1 = slot_pos[2 * tk + 1];
  float w0 = w[2 * tk], w1 = w[2 * tk + 1];
  uint4 ua = reinterpret_cast<const uint4*>(yws + (size_t)p0 * HID)[lane];
  uint4 ub = reinterpret_cast<const uint4*>(yws + (size_t)p1 * HID)[lane];
  float4 o0, o1;
  o0.x = w0 * bf2f(ua.x & 0xffffu) + w1 * bf2f(ub.x & 0xffffu);
  o0.y = w0 * bf2f(ua.x >> 16) + w1 * bf2f(ub.x >> 16);
  o0.z = w0 * bf2f(ua.y & 0xffffu) + w1 * bf2f(ub.y & 0xffffu);
  o0.w = w0 * bf2f(ua.y >> 16) + w1 * bf2f(ub.y >> 16);
  o1.x = w0 * bf2f(ua.z & 0xffffu) + w1 * bf2f(ub.z & 0xffffu);
  o1.y = w0 * bf2f(ua.z >> 16) + w1 * bf2f(ub.z >> 16);
  o1.z = w0 * bf2f(ua.w & 0xffffu) + w1 * bf2f(ub.w & 0xffffu);
  o1.w = w0 * bf2f(ua.w >> 16) + w1 * bf2f(ub.w >> 16);
  float4* dst = reinterpret_cast<float4*>(out + (size_t)tk * HID + lane * 8);
  dst[0] = o0;
  dst[1] = o1;
}

// ---------------------------------------------------------------- launcher
extern "C" void kernel_launch(void* const* d_in, const int* in_sizes, int n_in,
                              void* d_out, int out_size, void* d_ws, size_t ws_size,
                              hipStream_t stream) {
  const float* hs = (const float*)d_in[0];
  const float* wts = (const float*)d_in[1];
  const int* ids = (const int*)d_in[2];
  const float* W1 = (const float*)d_in[3];
  const float* W2 = (const float*)d_in[4];
  float* out = (float*)d_out;

  char* ws = (char*)d_ws;
  size_t o = 0;
  int* cnt = (int*)(ws + o);       o += 1024;
  int* slot_pos = (int*)(ws + o);  o += (size_t)NASSIGN * 4;
  int* tok_of = (int*)(ws + o);    o += (size_t)NASSIGN * 4;
  o = (o + 255) & ~(size_t)255;
  u16* Xg = (u16*)(ws + o);        o += (size_t)NASSIGN * HID * 2;      // 32 MB
  u16* hid = (u16*)(ws + o);       o += (size_t)NASSIGN * FFN * 2;      // 64 MB
  u16* yws = (u16*)(ws + o);       o += (size_t)NASSIGN * HID * 2;      // 32 MB

  hipMemsetAsync(cnt, 0, NEXP * sizeof(int), stream);
  k_route<<<(NASSIGN + 255) / 256, 256, 0, stream>>>(ids, cnt, tok_of, slot_pos);
  k_gather<<<NASSIGN / 4, 256, 0, stream>>>(hs, tok_of, Xg);
  k_gemm<HID, FFN, true><<<NEXP * (CAP / 256) * (FFN / 128), 512, 0, stream>>>(Xg, W1, hid);
  k_gemm<FFN, HID, false><<<NEXP * (CAP / 256) * (HID / 128), 512, 0, stream>>>(hid, W2, yws);
  k_combine<<<B_TOK / 4, 256, 0, stream>>>(yws, slot_pos, wts, out);
}

// Round 23
// 206.671 us; speedup vs baseline: 1.1173x; 1.1173x over previous
//
#include <hip/hip_runtime.h>
#include <hip/hip_bf16.h>

#define B_TOK 16384
#define TOPK 2
#define NEXP 64
#define HID 512
#define FFN 1024
#define NASSIGN (B_TOK * TOPK)   // 32768
#define CAP (NASSIGN / NEXP)     // 512 assignments per expert (balanced)

typedef unsigned short u16;
typedef __bf16 bf16_t;
typedef bf16_t bf16x8 __attribute__((ext_vector_type(8)));
typedef float f32x4 __attribute__((ext_vector_type(4)));

// native cvt: compiler emits v_cvt_pk_bf16_f32 (RTNE)
__device__ __forceinline__ unsigned pkbf(float a, float b) {
  union { bf16_t h[2]; unsigned u; } v;
  v.h[0] = (bf16_t)a; v.h[1] = (bf16_t)b;
  return v.u;
}
__device__ __forceinline__ u16 f2bf(float f) {
  union { bf16_t h; u16 u; } v; v.h = (bf16_t)f; return v.u;
}
__device__ __forceinline__ float bf2f(unsigned u16v) {
  union { unsigned u; float f; } v; v.u = u16v << 16; return v.f;
}

#define GLOAD_LDS16(g, l)                                                     \
  __builtin_amdgcn_global_load_lds((const __attribute__((address_space(1))) void*)(g), \
                                   (__attribute__((address_space(3))) void*)(l), 16, 0, 0)

// ---------------------------------------------------------------- routing
__global__ void k_route(const int* __restrict__ ids, int* __restrict__ cnt,
                        int* __restrict__ tok_of, int* __restrict__ slot_pos) {
  int n = blockIdx.x * blockDim.x + threadIdx.x;
  if (n >= NASSIGN) return;
  int e = ids[n];
  int r = atomicAdd(&cnt[e], 1);
  int p = e * CAP + r;
  tok_of[p] = n >> 1;       // token index for sorted slot p
  slot_pos[n] = p;          // inverse map: assignment n -> sorted slot
}

// ------------------------------------------------- gather + fp32->bf16 cast
__global__ void k_gather(const float* __restrict__ hs, const int* __restrict__ tok_of,
                         u16* __restrict__ Xg) {
  int p = blockIdx.x * 4 + (threadIdx.x >> 6);
  int lane = threadIdx.x & 63;
  const float4* src = reinterpret_cast<const float4*>(hs + (size_t)tok_of[p] * HID);
  uint2* dst = reinterpret_cast<uint2*>(Xg + (size_t)p * HID);
#pragma unroll
  for (int i = 0; i < 2; i++) {
    float4 v = src[i * 64 + lane];
    uint2 o;
    o.x = pkbf(v.x, v.y);
    o.y = pkbf(v.z, v.w);
    dst[i * 64 + lane] = o;
  }
}

// ------------------------------------------------------------ grouped GEMM
// FINAL (R18, twice-verified at 206.4/206.9 us total): minimal 2-phase
// K-loop, ONE barrier per K-tile.  Per tile t:
//   LOAD_L(t+1) [8 fp32x4] ; STAGE_A(t+1) -> OPPOSITE A-slot [4 DMA]
//   read a03 + b0123 (16 ds_read_b128) ; lgkm0 ; 32 MFMA
//   read a47 (8, reusing a[] regs)     ; lgkm0 ; 32 MFMA
//   vmcnt(4)  [queue = 8 L then 4 ADMA -> retires L exactly, ADMA in flight]
//   WRITE_B(t+1) -> OPPOSITE B-slot (4x uint4 swizzled)
//   vmcnt(0)+lgkm0 ; s_barrier        [ADMA had a full tile of cover]
// Safety: all ds_reads/writes of tile t drain (per-wave lgkm0) before the
// single trailing barrier; opp-slot readers (tile t-1) drained before the
// previous barrier; so DMA/writes into opp never race in-flight reads.
// Swizzles (both-sides, rule #21): A chunk c -> c^(row&7) (pre-swizzled
// global source, linear gload_lds dest); B chunk c -> c^S(n),
// S(n)=(n^(n>>3))&7 (reg-staged writes), matching ds_read addresses.
template <int K, int NN, bool SILU>
__global__ __launch_bounds__(512, 2) void k_gemm(const u16* __restrict__ A,
                                                 const float* __restrict__ Wf,
                                                 u16* __restrict__ Cout) {
  constexpr int MT = CAP / 256;        // 2
  constexpr int NT = NN / 256;
  constexpr int NWG = NEXP * MT * NT;  // %8 == 0
  constexpr int Q = NWG / 8;
  constexpr int KT = K / 64;           // 8 or 16
  int wg = (blockIdx.x % 8) * Q + blockIdx.x / 8;  // XCD chunked swizzle
  int e = wg / (MT * NT);
  int rm = wg % (MT * NT);
  int mt = rm / NT, nt = rm % NT;

  const u16* Ab = A + ((size_t)e * CAP + (size_t)mt * 256) * K;

  // LDS: A dbuf 2x32KB at 0; B dbuf 2x32KB at 65536. 128KB.
  __shared__ __align__(16) char smc[131072];

  int t_ = threadIdx.x;
  int lane = t_ & 63, wv = t_ >> 6;
  int wm = wv >> 2, wn = wv & 3;        // 2x4 wave grid; wave out = 128x64
  int l15 = lane & 15, lhi = lane >> 4;

  // ---- A staging (global_load_lds): row t_>>3, chunk pos t_&7, src chunk ^row&7
  int srow = t_ >> 3;
  int gchunk = (t_ & 7) ^ (srow & 7);
  const u16* gA = Ab + (size_t)srow * K + gchunk * 8;
#define STAGE_HALF_A(tn, j)                                                  \
  do {                                                                       \
    char* d_ = smc + ((tn) & 1) * 32768 + (j) * 16384 + wv * 1024;           \
    const u16* s_ = gA + (size_t)((j) * 128) * K + (tn) * 64;                \
    GLOAD_LDS16(s_, d_);                                                     \
    GLOAD_LDS16(s_ + (size_t)64 * K, d_ + 8192);                             \
  } while (0)

  // ---- B staging (reg-staged transpose+cvt from fp32 W[k][n])
  int kunit = t_ >> 6;                  // 0..7
  int nunit = t_ & 63;                  // 0..63
  const float* gWb = Wf + (size_t)e * K * NN + (size_t)(kunit * 8) * NN +
                     (size_t)nt * 256 + nunit * 4;
  int wbo[4];                           // byte offsets of the 4 write slots
#pragma unroll
  for (int i = 0; i < 4; i++) {
    int n = nunit * 4 + i;
    int S = (n ^ (n >> 3)) & 7;
    wbo[i] = n * 128 + ((kunit ^ S) << 4);
  }

  f32x4 acc[8][4];
#pragma unroll
  for (int i = 0; i < 8; i++)
#pragma unroll
    for (int j = 0; j < 4; j++) {
      f32x4 z = {0.f, 0.f, 0.f, 0.f};
      acc[i][j] = z;
    }
  bf16x8 a[4][2], b[4][2];

  // ---- fragment read offsets
  int aof0 = (wm * 128 + l15) * 128 + ((lhi ^ (l15 & 7)) << 4);
  int aof1 = (wm * 128 + l15) * 128 + (((4 + lhi) ^ (l15 & 7)) << 4);
  int boff[4][2];
#pragma unroll
  for (int nf = 0; nf < 4; nf++) {
    int r = wn * 64 + nf * 16 + l15;
    int Sr = (r ^ (r >> 3)) & 7;
    boff[nf][0] = r * 128 + ((lhi ^ Sr) << 4);
    boff[nf][1] = r * 128 + (((4 + lhi) ^ Sr) << 4);
  }

#define LGKM0()                                                              \
  do {                                                                       \
    asm volatile("s_waitcnt lgkmcnt(0)" ::: "memory");                       \
    __builtin_amdgcn_sched_barrier(0);                                       \
  } while (0)

#define MFMA_QUAD(mh, nh)                                                    \
  do {                                                                       \
    __builtin_amdgcn_s_setprio(1);                                           \
    _Pragma("unroll") for (int mf = 0; mf < 4; mf++)                         \
        _Pragma("unroll") for (int nf = 0; nf < 2; nf++)                     \
            _Pragma("unroll") for (int kk = 0; kk < 2; kk++)                 \
                acc[(mh)*4 + mf][(nh)*2 + nf] = __builtin_amdgcn_mfma_f32_16x16x32_bf16( \
                    a[mf][kk], b[(nh)*2 + nf][kk], acc[(mh)*4 + mf][(nh)*2 + nf], 0, 0, 0); \
    __builtin_amdgcn_s_setprio(0);                                           \
  } while (0)

  // ---- prologue: A(0) via DMA; L(0) -> B slot 0
  STAGE_HALF_A(0, 0); STAGE_HALF_A(0, 1);
  {
    float4 P[8];
#pragma unroll
    for (int j = 0; j < 8; j++)
      P[j] = *reinterpret_cast<const float4*>(gWb + (size_t)j * NN);
    asm volatile("s_waitcnt vmcnt(0)" ::: "memory");  // L(0) regs + A(0) resident
    __builtin_amdgcn_sched_barrier(0);
    char* wB = smc + 65536;  // slot 0
#pragma unroll
    for (int i = 0; i < 4; i++) {
      uint4 v;
      v.x = pkbf(P[0][i], P[1][i]); v.y = pkbf(P[2][i], P[3][i]);
      v.z = pkbf(P[4][i], P[5][i]); v.w = pkbf(P[6][i], P[7][i]);
      *reinterpret_cast<uint4*>(wB + wbo[i]) = v;
    }
  }
  LGKM0();
  __builtin_amdgcn_s_barrier();

  for (int t = 0; t < KT; t++) {
    const char* pA = smc + (t & 1) * 32768;
    const char* pB = smc + 65536 + (t & 1) * 32768;
    char* wB = smc + 65536 + ((t + 1) & 1) * 32768;
    float4 L0, L1, L2, L3, L4, L5, L6, L7;

    // issue next-tile loads first: 8 L (oldest), then 4 A-DMA
    if (t + 1 < KT) {
      const float* g = gWb + (size_t)(t + 1) * 64 * NN;
      L0 = *reinterpret_cast<const float4*>(g);
      L1 = *reinterpret_cast<const float4*>(g + (size_t)1 * NN);
      L2 = *reinterpret_cast<const float4*>(g + (size_t)2 * NN);
      L3 = *reinterpret_cast<const float4*>(g + (size_t)3 * NN);
      L4 = *reinterpret_cast<const float4*>(g + (size_t)4 * NN);
      L5 = *reinterpret_cast<const float4*>(g + (size_t)5 * NN);
      L6 = *reinterpret_cast<const float4*>(g + (size_t)6 * NN);
      L7 = *reinterpret_cast<const float4*>(g + (size_t)7 * NN);
      STAGE_HALF_A(t + 1, 0); STAGE_HALF_A(t + 1, 1);
    }

    // ---- half 1: a03 + all b frags; 32 MFMA
#pragma unroll
    for (int mf = 0; mf < 4; mf++) {
      a[mf][0] = *reinterpret_cast<const bf16x8*>(pA + aof0 + mf * 2048);
      a[mf][1] = *reinterpret_cast<const bf16x8*>(pA + aof1 + mf * 2048);
    }
#pragma unroll
    for (int nf = 0; nf < 4; nf++) {
      b[nf][0] = *reinterpret_cast<const bf16x8*>(pB + boff[nf][0]);
      b[nf][1] = *reinterpret_cast<const bf16x8*>(pB + boff[nf][1]);
    }
    LGKM0();
    MFMA_QUAD(0, 0);
    MFMA_QUAD(0, 1);

    // ---- half 2: a47 (reuse a[] regs); 32 MFMA
#pragma unroll
    for (int mf = 0; mf < 4; mf++) {
      a[mf][0] = *reinterpret_cast<const bf16x8*>(pA + aof0 + (4 + mf) * 2048);
      a[mf][1] = *reinterpret_cast<const bf16x8*>(pA + aof1 + (4 + mf) * 2048);
    }
    LGKM0();
    MFMA_QUAD(1, 0);
    MFMA_QUAD(1, 1);

    // ---- stage B(t+1) from L regs; single barrier
    if (t + 1 < KT) {
      asm volatile("s_waitcnt vmcnt(4)" ::: "memory");  // L retired; ADMA in flight
      __builtin_amdgcn_sched_barrier(0);
#pragma unroll
      for (int i = 0; i < 4; i++) {
        uint4 v;
        v.x = pkbf(L0[i], L1[i]); v.y = pkbf(L2[i], L3[i]);
        v.z = pkbf(L4[i], L5[i]); v.w = pkbf(L6[i], L7[i]);
        *reinterpret_cast<uint4*>(wB + wbo[i]) = v;
      }
      asm volatile("s_waitcnt vmcnt(0) lgkmcnt(0)" ::: "memory");  // ADMA + B-writes drained
      __builtin_amdgcn_sched_barrier(0);
      __builtin_amdgcn_s_barrier();
    }
  }
#undef STAGE_HALF_A
#undef MFMA_QUAD
#undef LGKM0

  // epilogue: D row = lhi*4+reg, col = l15 (verified C/D layout); bf16 out
#pragma unroll
  for (int mf = 0; mf < 8; mf++) {
#pragma unroll
    for (int nf = 0; nf < 4; nf++) {
#pragma unroll
      for (int rg = 0; rg < 4; rg++) {
        float v = acc[mf][nf][rg];
        int grow = mt * 256 + wm * 128 + mf * 16 + lhi * 4 + rg;
        int gcol = nt * 256 + wn * 64 + nf * 16 + l15;
        size_t off = ((size_t)e * CAP + grow) * NN + gcol;
        if constexpr (SILU) v = v / (1.0f + __expf(-v));  // silu
        Cout[off] = f2bf(v);
      }
    }
  }
}

// ------------------------------------------- weighted combine (no atomics)
// wave per token: lane reads uint4 (8 bf16) per slot row, writes 2 float4.
__global__ void k_combine(const u16* __restrict__ yws, const int* __restrict__ slot_pos,
                          const float* __restrict__ w, float* __restrict__ out) {
  int tk = blockIdx.x * 4 + (threadIdx.x >> 6);
  int lane = threadIdx.x & 63;
  int p0 = slot_pos[2 * tk], p1 = slot_pos[2 * tk + 1];
  float w0 = w[2 * tk], w1 = w[2 * tk + 1];
  uint4 ua = reinterpret_cast<const uint4*>(yws + (size_t)p0 * HID)[lane];
  uint4 ub = reinterpret_cast<const uint4*>(yws + (size_t)p1 * HID)[lane];
  float4 o0, o1;
  o0.x = w0 * bf2f(ua.x & 0xffffu) + w1 * bf2f(ub.x & 0xffffu);
  o0.y = w0 * bf2f(ua.x >> 16) + w1 * bf2f(ub.x >> 16);
  o0.z = w0 * bf2f(ua.y & 0xffffu) + w1 * bf2f(ub.y & 0xffffu);
  o0.w = w0 * bf2f(ua.y >> 16) + w1 * bf2f(ub.y >> 16);
  o1.x = w0 * bf2f(ua.z & 0xffffu) + w1 * bf2f(ub.z & 0xffffu);
  o1.y = w0 * bf2f(ua.z >> 16) + w1 * bf2f(ub.z >> 16);
  o1.z = w0 * bf2f(ua.w & 0xffffu) + w1 * bf2f(ub.w & 0xffffu);
  o1.w = w0 * bf2f(ua.w >> 16) + w1 * bf2f(ub.w >> 16);
  float4* dst = reinterpret_cast<float4*>(out + (size_t)tk * HID + lane * 8);
  dst[0] = o0;
  dst[1] = o1;
}

// ---------------------------------------------------------------- launcher
extern "C" void kernel_launch(void* const* d_in, const int* in_sizes, int n_in,
                              void* d_out, int out_size, void* d_ws, size_t ws_size,
                              hipStream_t stream) {
  const float* hs = (const float*)d_in[0];
  const float* wts = (const float*)d_in[1];
  const int* ids = (const int*)d_in[2];
  const float* W1 = (const float*)d_in[3];
  const float* W2 = (const float*)d_in[4];
  float* out = (float*)d_out;

  char* ws = (char*)d_ws;
  size_t o = 0;
  int* cnt = (int*)(ws + o);       o += 1024;
  int* slot_pos = (int*)(ws + o);  o += (size_t)NASSIGN * 4;
  int* tok_of = (int*)(ws + o);    o += (size_t)NASSIGN * 4;
  o = (o + 255) & ~(size_t)255;
  u16* Xg = (u16*)(ws + o);        o += (size_t)NASSIGN * HID * 2;      // 32 MB
  u16* hid = (u16*)(ws + o);       o += (size_t)NASSIGN * FFN * 2;      // 64 MB
  u16* yws = (u16*)(ws + o);       o += (size_t)NASSIGN * HID * 2;      // 32 MB

  hipMemsetAsync(cnt, 0, NEXP * sizeof(int), stream);
  k_route<<<(NASSIGN + 255) / 256, 256, 0, stream>>>(ids, cnt, tok_of, slot_pos);
  k_gather<<<NASSIGN / 4, 256, 0, stream>>>(hs, tok_of, Xg);
  k_gemm<HID, FFN, true><<<NEXP * (CAP / 256) * (FFN / 256), 512, 0, stream>>>(Xg, W1, hid);
  k_gemm<FFN, HID, false><<<NEXP * (CAP / 256) * (HID / 256), 512, 0, stream>>>(hid, W2, yws);
  k_combine<<<B_TOK / 4, 256, 0, stream>>>(yws, slot_pos, wts, out);
}